// Round 12
// baseline (255.528 us; speedup 1.0000x reference)
//
#include <hip/hip_runtime.h>
#include <math.h>

// ---------------------------------------------------------------------------
// GAT 2-layer (PyG GATConv eval) on gfx950.
// R12: gemm1 single-pass BN=256 (x read once, was twice); gemm2 BK=64
//      (half the barriers); agg_single prefetch depth 4.
// R11: BK=32 gemm1 + 5-dispatch CSR. R9: fused alpha epilogues.
// R8/R7: MLP-tuned agg kernels — agg_multi at random-gather HBM ceiling
//        (FETCH 207MB = 8 XCDs x full 25.6MB table, compulsory).
// ---------------------------------------------------------------------------

typedef unsigned short u16;
typedef short s8v __attribute__((ext_vector_type(8)));    // 8 bf16 (4 VGPR)
typedef float f32x4 __attribute__((ext_vector_type(4)));  // MFMA acc

#define LOG2E 1.4426950408889634f

__device__ __forceinline__ float bflo(unsigned int u) {
  return __builtin_bit_cast(float, u << 16);
}
__device__ __forceinline__ float bfhi(unsigned int u) {
  return __builtin_bit_cast(float, u & 0xffff0000u);
}
__device__ __forceinline__ u16 f2bf(float f) {  // RNE
  unsigned int u = __builtin_bit_cast(unsigned int, f);
  return (u16)((u + 0x7fff + ((u >> 16) & 1)) >> 16);
}

// ---- CSR count + W transposes (merged, independent ranges) ------------------

__global__ void prep_count_kernel(const int* __restrict__ ei, int E, int Nn,
                                  int* __restrict__ deg,
                                  const float* __restrict__ W1, u16* __restrict__ W1T,
                                  const float* __restrict__ W2, u16* __restrict__ W2T) {
  int i = blockIdx.x * blockDim.x + threadIdx.x;
  int Et = E + Nn;
  if (i < Et) {
    int dst = (i < E) ? ei[E + i] : (i - E);  // self-loops appended
    atomicAdd(&deg[dst], 1);
    return;
  }
  int e = i - Et;
  if (e < 128 * 256) {                        // W1 [128][256] -> W1T [256][128]
    int k = e >> 8, n = e & 255;
    W1T[n * 128 + k] = f2bf(W1[e]);
    return;
  }
  e -= 128 * 256;
  if (e < 256 * 64) {                         // W2 [256][64] -> W2T [64][256]
    int k = e >> 6, n = e & 63;
    W2T[n * 256 + k] = f2bf(W2[e]);
  }
}

__global__ void scan_partials_kernel(const int* __restrict__ deg,
                                     int* __restrict__ partials, int Ntot) {
  __shared__ int red[256];
  int t = threadIdx.x;
  int base = blockIdx.x * 1024 + t * 4;
  int s = 0;
  if (base + 3 < Ntot) {
    int4 v = *(const int4*)(deg + base);
    s = v.x + v.y + v.z + v.w;
  } else {
    for (int i = 0; i < 4; ++i)
      if (base + i < Ntot) s += deg[base + i];
  }
  red[t] = s;
  __syncthreads();
  for (int off = 128; off > 0; off >>= 1) {
    if (t < off) red[t] += red[t + off];
    __syncthreads();
  }
  if (t == 0) partials[blockIdx.x] = red[0];
}

__global__ void scan_final_kernel(const int* __restrict__ deg,
                                  const int* __restrict__ partials,
                                  int* __restrict__ rowptr,
                                  int* __restrict__ cursor, int Ntot, int NB) {
  __shared__ int sums[256];
  int t = threadIdx.x;
  int bid = blockIdx.x;
  int base = bid * 1024 + t * 4;
  int4 v = make_int4(0, 0, 0, 0);
  if (base + 3 < Ntot) {
    v = *(const int4*)(deg + base);
  } else {
    if (base + 0 < Ntot) v.x = deg[base + 0];
    if (base + 1 < Ntot) v.y = deg[base + 1];
    if (base + 2 < Ntot) v.z = deg[base + 2];
    if (base + 3 < Ntot) v.w = deg[base + 3];
  }
  sums[t] = v.x + v.y + v.z + v.w;
  __syncthreads();
  for (int off = 1; off < 256; off <<= 1) {
    int u = (t >= off) ? sums[t - off] : 0;
    __syncthreads();
    sums[t] += u;
    __syncthreads();
  }
  int boff = 0;
  for (int j = 0; j < bid; ++j) boff += partials[j];  // <=48 uniform iters
  int excl = boff + ((t == 0) ? 0 : sums[t - 1]);
  int4 r;
  r.x = excl;
  r.y = r.x + v.x;
  r.z = r.y + v.y;
  r.w = r.z + v.z;
  if (base + 3 < Ntot) {
    *(int4*)(rowptr + base) = r;
    *(int4*)(cursor + base) = r;
  } else {
    if (base + 0 < Ntot) { rowptr[base + 0] = r.x; cursor[base + 0] = r.x; }
    if (base + 1 < Ntot) { rowptr[base + 1] = r.y; cursor[base + 1] = r.y; }
    if (base + 2 < Ntot) { rowptr[base + 2] = r.z; cursor[base + 2] = r.z; }
    if (base + 3 < Ntot) { rowptr[base + 3] = r.w; cursor[base + 3] = r.w; }
  }
}

__global__ void scatter_edges_kernel(const int* __restrict__ ei, int E, int Nn,
                                     int* __restrict__ cursor, int* __restrict__ col) {
  int e = blockIdx.x * blockDim.x + threadIdx.x;
  if (e >= E + Nn) return;
  int src, dst;
  if (e < E) { src = ei[e]; dst = ei[E + e]; }
  else       { src = dst = e - E; }
  int pos = atomicAdd(&cursor[dst], 1);
  col[pos] = src;
}

// ---- GEMM1 fused: xl1 = bf16(x) @ W1, + alpha1 in epilogue ------------------
// BM=128, BN=256 (full width, x read ONCE), BK=32, 4 waves 2x2,
// wave tile 64x128 (NJ=8 -> 2 heads per wave).

__global__ __launch_bounds__(256) void gemm1_fused_kernel(
    const float* __restrict__ x,      // [M][128] fp32
    const u16* __restrict__ w1t,      // [256][128] bf16
    const float* __restrict__ a_src,  // [4][64] fp32
    const float* __restrict__ a_dst,
    u16* __restrict__ C,              // [Mpad][256] bf16
    float* __restrict__ asrc, float* __restrict__ adst,  // [M*4]
    int M) {
  constexpr int BM = 128, BK = 32, PK = 40;
  __shared__ short As[BM][PK];
  __shared__ short Bs[256][PK];
  int tid = threadIdx.x;
  int lane = tid & 63, w = tid >> 6;
  int q = lane >> 4, fr = lane & 15;
  int wm = (w >> 1) * 64, wn = (w & 1) * 128;
  int bm0 = blockIdx.x * BM;
  int fk = q * 8;

  f32x4 acc[4][8] = {};

  for (int k0 = 0; k0 < 128; k0 += BK) {
#pragma unroll
    for (int p = 0; p < 4; ++p) {              // A: 128x32 fp32 -> bf16
      int idx = p * 1024 + tid * 4;
      int r = idx >> 5, c = idx & 31;
      float4 v = make_float4(0.f, 0.f, 0.f, 0.f);
      if (bm0 + r < M) v = *(const float4*)(x + (size_t)(bm0 + r) * 128 + k0 + c);
      *(ushort4*)&As[r][c] = make_ushort4(f2bf(v.x), f2bf(v.y), f2bf(v.z), f2bf(v.w));
    }
#pragma unroll
    for (int p = 0; p < 4; ++p) {              // B: 256x32 bf16
      int idx = p * 2048 + tid * 8;
      int r = idx >> 5, c = idx & 31;
      *(s8v*)&Bs[r][c] = *(const s8v*)(w1t + (size_t)r * 128 + k0 + c);
    }
    __syncthreads();

    s8v af[4], bf[8];
#pragma unroll
    for (int i = 0; i < 4; ++i)
      af[i] = *(const s8v*)&As[wm + i * 16 + fr][fk];
#pragma unroll
    for (int j = 0; j < 8; ++j)
      bf[j] = *(const s8v*)&Bs[wn + j * 16 + fr][fk];
#pragma unroll
    for (int i = 0; i < 4; ++i)
#pragma unroll
      for (int j = 0; j < 8; ++j)
        acc[i][j] = __builtin_amdgcn_mfma_f32_16x16x32_bf16(af[i], bf[j], acc[i][j], 0, 0, 0);
    __syncthreads();
  }

  // epilogue: two heads per wave (h0 = cols wn..wn+63, h0+1 = wn+64..wn+127)
  int h0 = wn >> 6;
  float asv[8], adv[8];
#pragma unroll
  for (int j = 0; j < 8; ++j) {
    asv[j] = a_src[wn + j * 16 + fr];   // flat [4*64] = [h][c]
    adv[j] = a_dst[wn + j * 16 + fr];
  }
#pragma unroll
  for (int i = 0; i < 4; ++i) {
#pragma unroll
    for (int r = 0; r < 4; ++r) {
      int row = bm0 + wm + i * 16 + q * 4 + r;
      float ps0 = 0.f, pd0 = 0.f, ps1 = 0.f, pd1 = 0.f;
#pragma unroll
      for (int j = 0; j < 4; ++j) {
        ps0 = fmaf(acc[i][j][r], asv[j], ps0);
        pd0 = fmaf(acc[i][j][r], adv[j], pd0);
        ps1 = fmaf(acc[i][j + 4][r], asv[j + 4], ps1);
        pd1 = fmaf(acc[i][j + 4][r], adv[j + 4], pd1);
      }
#pragma unroll
      for (int mmask = 1; mmask < 16; mmask <<= 1) {
        ps0 += __shfl_xor(ps0, mmask, 64);
        pd0 += __shfl_xor(pd0, mmask, 64);
        ps1 += __shfl_xor(ps1, mmask, 64);
        pd1 += __shfl_xor(pd1, mmask, 64);
      }
      if (fr == 0 && row < M) {
        asrc[row * 4 + h0] = ps0 * LOG2E;
        adst[row * 4 + h0] = pd0 * LOG2E;
        asrc[row * 4 + h0 + 1] = ps1 * LOG2E;
        adst[row * 4 + h0 + 1] = pd1 * LOG2E;
      }
    }
  }
#pragma unroll
  for (int i = 0; i < 4; ++i)
#pragma unroll
    for (int j = 0; j < 8; ++j)
#pragma unroll
      for (int r = 0; r < 4; ++r) {
        int row = bm0 + wm + i * 16 + q * 4 + r;
        if (row < M)
          C[(size_t)row * 256 + wn + j * 16 + fr] = f2bf(acc[i][j][r]);
      }
}

// ---- GEMM2 fused: xl2 = hb @ W2, + alpha2 in epilogue (LDS cross-wave) ------
// BK=64 (4 K-iters, 8 barriers total).

__global__ __launch_bounds__(256) void gemm2_fused_kernel(
    const u16* __restrict__ A,        // hb [Mpad][256] bf16
    const u16* __restrict__ Bt,       // w2t [64][256] bf16
    const float* __restrict__ a_src,  // [64]
    const float* __restrict__ a_dst,
    u16* __restrict__ C,              // [Mpad][64] bf16
    float* __restrict__ asrc, float* __restrict__ adst,  // [M]
    int M) {
  constexpr int BM = 128, BN = 64, BK = 64, PK = 72;
  __shared__ short As[BM][PK];
  __shared__ short Bs[BN][PK];
  __shared__ float alds[BM][4];
  int tid = threadIdx.x;
  int lane = tid & 63, w = tid >> 6;
  int q = lane >> 4, fr = lane & 15;
  int wm = (w >> 1) * 64, wn = (w & 1) * 32;
  int bm0 = blockIdx.x * BM;
  int fk = q * 8;

  f32x4 acc[4][2] = {};

  for (int k0 = 0; k0 < 256; k0 += BK) {
#pragma unroll
    for (int p = 0; p < 4; ++p) {
      int idx = p * 2048 + tid * 8;
      int r = idx / BK, c = idx % BK;
      *(s8v*)&As[r][c] = *(const s8v*)(A + (size_t)(bm0 + r) * 256 + k0 + c);
    }
#pragma unroll
    for (int p = 0; p < 2; ++p) {
      int idx = p * 2048 + tid * 8;
      int r = idx / BK, c = idx % BK;
      *(s8v*)&Bs[r][c] = *(const s8v*)(Bt + (size_t)r * 256 + k0 + c);
    }
    __syncthreads();

#pragma unroll
    for (int ks = 0; ks < 2; ++ks) {
      s8v af[4], bf[2];
#pragma unroll
      for (int i = 0; i < 4; ++i)
        af[i] = *(const s8v*)&As[wm + i * 16 + fr][ks * 32 + fk];
#pragma unroll
      for (int j = 0; j < 2; ++j)
        bf[j] = *(const s8v*)&Bs[wn + j * 16 + fr][ks * 32 + fk];
#pragma unroll
      for (int i = 0; i < 4; ++i)
#pragma unroll
        for (int j = 0; j < 2; ++j)
          acc[i][j] = __builtin_amdgcn_mfma_f32_16x16x32_bf16(af[i], bf[j], acc[i][j], 0, 0, 0);
    }
    __syncthreads();
  }

  float asv[2], adv[2];
#pragma unroll
  for (int j = 0; j < 2; ++j) {
    asv[j] = a_src[wn + j * 16 + fr];
    adv[j] = a_dst[wn + j * 16 + fr];
  }
#pragma unroll
  for (int i = 0; i < 4; ++i) {
#pragma unroll
    for (int r = 0; r < 4; ++r) {
      int lr = wm + i * 16 + q * 4 + r;
      float ps = 0.f, pd = 0.f;
#pragma unroll
      for (int j = 0; j < 2; ++j) {
        ps = fmaf(acc[i][j][r], asv[j], ps);
        pd = fmaf(acc[i][j][r], adv[j], pd);
      }
#pragma unroll
      for (int mmask = 1; mmask < 16; mmask <<= 1) {
        ps += __shfl_xor(ps, mmask, 64);
        pd += __shfl_xor(pd, mmask, 64);
      }
      if (fr == 0) {
        alds[lr][(w & 1) * 2 + 0] = ps;
        alds[lr][(w & 1) * 2 + 1] = pd;
      }
    }
  }
#pragma unroll
  for (int i = 0; i < 4; ++i)
#pragma unroll
    for (int j = 0; j < 2; ++j)
#pragma unroll
      for (int r = 0; r < 4; ++r) {
        int row = bm0 + wm + i * 16 + q * 4 + r;
        if (row < M)
          C[(size_t)row * 64 + wn + j * 16 + fr] = f2bf(acc[i][j][r]);
      }
  __syncthreads();
  if (tid < BM) {
    int row = bm0 + tid;
    if (row < M) {
      asrc[row] = (alds[tid][0] + alds[tid][2]) * LOG2E;
      adst[row] = (alds[tid][1] + alds[tid][3]) * LOG2E;
    }
  }
}

// ---- layer-1 aggregation: half-wave (32 lanes) per node, 8 ch/lane ----------

__global__ void agg_multi_kernel(const u16* __restrict__ xlb,
                                 const float* __restrict__ asrc,
                                 const float* __restrict__ adst,
                                 const int* __restrict__ rowptr,
                                 const int* __restrict__ col,
                                 const float* __restrict__ bias,
                                 u16* __restrict__ hb, int Nn) {
  int n = blockIdx.x * 8 + (threadIdx.x >> 5);
  if (n >= Nn) return;
  int lane = threadIdx.x & 31;
  int h = lane >> 3;                          // 8 lanes per head
  float adn = adst[n * 4 + h];
  int beg = rowptr[n], end = rowptr[n + 1];

  float s = 0.f;
  float acc[8] = {};

  float as0 = 0.f, as1 = 0.f, as2 = 0.f, as3 = 0.f;
  uint4 v0 = {}, v1 = {}, v2 = {}, v3 = {};
  {
    int sc = col[beg];
    as0 = asrc[sc * 4 + h];
    v0 = *(const uint4*)(xlb + (size_t)sc * 256 + lane * 8);
    if (beg + 1 < end) {
      int c1 = col[beg + 1];
      as1 = asrc[c1 * 4 + h];
      v1 = *(const uint4*)(xlb + (size_t)c1 * 256 + lane * 8);
    }
    if (beg + 2 < end) {
      int c2 = col[beg + 2];
      as2 = asrc[c2 * 4 + h];
      v2 = *(const uint4*)(xlb + (size_t)c2 * 256 + lane * 8);
    }
    if (beg + 3 < end) {
      int c3 = col[beg + 3];
      as3 = asrc[c3 * 4 + h];
      v3 = *(const uint4*)(xlb + (size_t)c3 * 256 + lane * 8);
    }
  }

  for (int i = beg; i < end; ++i) {
    float e = as0 + adn;
    e = fmaxf(e, 0.2f * e);                   // leaky_relu (log2-scaled)
    uint4 vc = v0;
    as0 = as1; v0 = v1;                       // shift pipeline
    as1 = as2; v1 = v2;
    as2 = as3; v2 = v3;
    if (i + 4 < end) {
      int sc = col[i + 4];
      as3 = asrc[sc * 4 + h];
      v3 = *(const uint4*)(xlb + (size_t)sc * 256 + lane * 8);
    }
    float w = __builtin_amdgcn_exp2f(e);
    s += w;
    acc[0] = fmaf(w, bflo(vc.x), acc[0]);
    acc[1] = fmaf(w, bfhi(vc.x), acc[1]);
    acc[2] = fmaf(w, bflo(vc.y), acc[2]);
    acc[3] = fmaf(w, bfhi(vc.y), acc[3]);
    acc[4] = fmaf(w, bflo(vc.z), acc[4]);
    acc[5] = fmaf(w, bfhi(vc.z), acc[5]);
    acc[6] = fmaf(w, bflo(vc.w), acc[6]);
    acc[7] = fmaf(w, bfhi(vc.w), acc[7]);
  }
  float inv_s = 1.f / s;

  float4 b0 = *(const float4*)(bias + lane * 8);
  float4 b1f = *(const float4*)(bias + lane * 8 + 4);
  float bb[8] = {b0.x, b0.y, b0.z, b0.w, b1f.x, b1f.y, b1f.z, b1f.w};
  u16 ov[8];
#pragma unroll
  for (int j = 0; j < 8; ++j) {
    float o = fmaf(acc[j], inv_s, bb[j]);
    o = (o > 0.f) ? o : __expf(o) - 1.f;      // ELU
    ov[j] = f2bf(o);
  }
  *(uint4*)(hb + (size_t)n * 256 + lane * 8) = *(uint4*)ov;
}

// ---- layer-2 aggregation: 8 lanes/node, uint4 = full 128B row, depth-4 ------

__global__ void agg_single_kernel(const u16* __restrict__ xlb,
                                  const float* __restrict__ asrc,
                                  const float* __restrict__ adst,
                                  const int* __restrict__ rowptr,
                                  const int* __restrict__ col,
                                  const float* __restrict__ bias,
                                  float* __restrict__ out, int Nn) {
  int n = blockIdx.x * 32 + (threadIdx.x >> 3);
  if (n >= Nn) return;
  int lane = threadIdx.x & 7;                 // 8 lanes, 8 ch each
  float adn = adst[n];
  int beg = rowptr[n], end = rowptr[n + 1];

  float s = 0.f;
  float acc[8] = {};

  float as0 = 0.f, as1 = 0.f, as2 = 0.f, as3 = 0.f;
  uint4 v0 = {}, v1 = {}, v2 = {}, v3 = {};
  {
    int sc = col[beg];
    as0 = asrc[sc];
    v0 = *(const uint4*)(xlb + (size_t)sc * 64 + lane * 8);
    if (beg + 1 < end) {
      int c1 = col[beg + 1];
      as1 = asrc[c1];
      v1 = *(const uint4*)(xlb + (size_t)c1 * 64 + lane * 8);
    }
    if (beg + 2 < end) {
      int c2 = col[beg + 2];
      as2 = asrc[c2];
      v2 = *(const uint4*)(xlb + (size_t)c2 * 64 + lane * 8);
    }
    if (beg + 3 < end) {
      int c3 = col[beg + 3];
      as3 = asrc[c3];
      v3 = *(const uint4*)(xlb + (size_t)c3 * 64 + lane * 8);
    }
  }

  for (int i = beg; i < end; ++i) {
    float e = as0 + adn;
    e = fmaxf(e, 0.2f * e);
    uint4 vc = v0;
    as0 = as1; v0 = v1;                       // shift pipeline
    as1 = as2; v1 = v2;
    as2 = as3; v2 = v3;
    if (i + 4 < end) {
      int sc = col[i + 4];
      as3 = asrc[sc];
      v3 = *(const uint4*)(xlb + (size_t)sc * 64 + lane * 8);
    }
    float w = __builtin_amdgcn_exp2f(e);
    s += w;
    acc[0] = fmaf(w, bflo(vc.x), acc[0]);
    acc[1] = fmaf(w, bfhi(vc.x), acc[1]);
    acc[2] = fmaf(w, bflo(vc.y), acc[2]);
    acc[3] = fmaf(w, bfhi(vc.y), acc[3]);
    acc[4] = fmaf(w, bflo(vc.z), acc[4]);
    acc[5] = fmaf(w, bfhi(vc.z), acc[5]);
    acc[6] = fmaf(w, bflo(vc.w), acc[6]);
    acc[7] = fmaf(w, bfhi(vc.w), acc[7]);
  }
  float inv_s = 1.f / s;

  const float* bp = bias + lane * 8;
  float4 o0, o1;
  o0.x = fmaf(acc[0], inv_s, bp[0]);
  o0.y = fmaf(acc[1], inv_s, bp[1]);
  o0.z = fmaf(acc[2], inv_s, bp[2]);
  o0.w = fmaf(acc[3], inv_s, bp[3]);
  o1.x = fmaf(acc[4], inv_s, bp[4]);
  o1.y = fmaf(acc[5], inv_s, bp[5]);
  o1.z = fmaf(acc[6], inv_s, bp[6]);
  o1.w = fmaf(acc[7], inv_s, bp[7]);
  *(float4*)(out + (size_t)n * 64 + lane * 8) = o0;
  *(float4*)(out + (size_t)n * 64 + lane * 8 + 4) = o1;
}

// ---------------------------------------------------------------------------

extern "C" void kernel_launch(void* const* d_in, const int* in_sizes, int n_in,
                              void* d_out, int out_size, void* d_ws, size_t ws_size,
                              hipStream_t stream) {
  const float* x   = (const float*)d_in[0];
  const int*   ei  = (const int*)d_in[1];
  const float* W1  = (const float*)d_in[2];
  const float* as1 = (const float*)d_in[3];
  const float* ad1 = (const float*)d_in[4];
  const float* b1  = (const float*)d_in[5];
  const float* W2  = (const float*)d_in[6];
  const float* as2 = (const float*)d_in[7];
  const float* ad2 = (const float*)d_in[8];
  const float* b2  = (const float*)d_in[9];
  float* out = (float*)d_out;

  const int Nn = in_sizes[0] / 128;  // 50000
  const int E  = in_sizes[1] / 2;    // 800000
  const int Et = E + Nn;
  const int Ntot = Nn + 1;           // scan domain (virtual deg[Nn]=0)
  const int NB = (Ntot + 1023) / 1024;
  const int MB = (Nn + 127) / 128;
  const int Mpad = MB * 128;

  char* base = (char*)d_ws;
  size_t off = 0;
  auto alloc = [&](size_t bytes) -> void* {
    void* p = base + off;
    off = (off + bytes + 255) & ~(size_t)255;
    return p;
  };
  u16*   w1t      = (u16*)alloc((size_t)256 * 128 * 2);    // W1^T bf16 [256][128]
  u16*   w2t      = (u16*)alloc((size_t)64 * 256 * 2);     // W2^T bf16 [64][256]
  u16*   xlb1     = (u16*)alloc((size_t)Mpad * 256 * 2);   // x@W1, bf16
  u16*   hb       = (u16*)alloc((size_t)Mpad * 256 * 2);   // ELU output, bf16
  float* asrc1    = (float*)alloc((size_t)Nn * 4 * 4);
  float* adst1    = (float*)alloc((size_t)Nn * 4 * 4);
  float* asrc2    = (float*)alloc((size_t)Nn * 4);
  float* adst2    = (float*)alloc((size_t)Nn * 4);
  int*   deg      = (int*)alloc((size_t)(Ntot + 8) * 4);
  int*   rowptr   = (int*)alloc((size_t)(Ntot + 8) * 4);
  int*   cursor   = (int*)alloc((size_t)(Ntot + 8) * 4);
  int*   partials = (int*)alloc(256 * 4);
  int*   col      = (int*)alloc((size_t)Et * 4);
  u16*   xlb2     = xlb1;  // layer2 h@W2 bf16 [Mpad][64], aliases xlb1

  // --- CSR build + W prep (5 small dispatches; gaps ~1-2us each) ---
  hipMemsetAsync(deg, 0, (size_t)Ntot * 4, stream);
  {
    int tot = Et + 128 * 256 + 256 * 64;
    prep_count_kernel<<<(tot + 255) / 256, 256, 0, stream>>>(
        ei, E, Nn, deg, W1, w1t, W2, w2t);
  }
  scan_partials_kernel<<<NB, 256, 0, stream>>>(deg, partials, Ntot);
  scan_final_kernel<<<NB, 256, 0, stream>>>(deg, partials, rowptr, cursor, Ntot, NB);
  scatter_edges_kernel<<<(Et + 255) / 256, 256, 0, stream>>>(ei, E, Nn, cursor, col);

  // --- layer 1 ---
  gemm1_fused_kernel<<<MB, 256, 0, stream>>>(x, w1t, as1, ad1, xlb1, asrc1, adst1, Nn);
  agg_multi_kernel<<<(Nn + 7) / 8, 256, 0, stream>>>(xlb1, asrc1, adst1, rowptr, col, b1, hb, Nn);

  // --- layer 2 ---
  gemm2_fused_kernel<<<MB, 256, 0, stream>>>(hb, w2t, as2, ad2, xlb2, asrc2, adst2, Nn);
  agg_single_kernel<<<(Nn + 31) / 32, 256, 0, stream>>>(xlb2, asrc2, adst2, rowptr, col, b2, out, Nn);
}

// Round 13
// 245.406 us; speedup vs baseline: 1.0412x; 1.0412x over previous
//
#include <hip/hip_runtime.h>
#include <math.h>

// ---------------------------------------------------------------------------
// GAT 2-layer (PyG GATConv eval) on gfx950.
// R13: revert R12 (BN=256 gemm1 cost occupancy: 128 acc VGPRs -> ~1 blk/CU;
//      traffic saved < occupancy lost). Exact R11 config = best known 245.7us.
// R11: BK=32 gemm1 + 5-dispatch CSR. R9: fused alpha epilogues.
// R8/R7: MLP-tuned agg kernels — agg_multi at random-gather HBM ceiling
//        (FETCH 207MB = 8 XCDs x full 25.6MB table, compulsory).
// R6: max-free softmax (exp2, log2e folded into alpha).
// ---------------------------------------------------------------------------

typedef unsigned short u16;
typedef short s8v __attribute__((ext_vector_type(8)));    // 8 bf16 (4 VGPR)
typedef float f32x4 __attribute__((ext_vector_type(4)));  // MFMA acc

#define LOG2E 1.4426950408889634f

__device__ __forceinline__ float bflo(unsigned int u) {
  return __builtin_bit_cast(float, u << 16);
}
__device__ __forceinline__ float bfhi(unsigned int u) {
  return __builtin_bit_cast(float, u & 0xffff0000u);
}
__device__ __forceinline__ u16 f2bf(float f) {  // RNE
  unsigned int u = __builtin_bit_cast(unsigned int, f);
  return (u16)((u + 0x7fff + ((u >> 16) & 1)) >> 16);
}

// ---- CSR count + W transposes (merged, independent ranges) ------------------

__global__ void prep_count_kernel(const int* __restrict__ ei, int E, int Nn,
                                  int* __restrict__ deg,
                                  const float* __restrict__ W1, u16* __restrict__ W1T,
                                  const float* __restrict__ W2, u16* __restrict__ W2T) {
  int i = blockIdx.x * blockDim.x + threadIdx.x;
  int Et = E + Nn;
  if (i < Et) {
    int dst = (i < E) ? ei[E + i] : (i - E);  // self-loops appended
    atomicAdd(&deg[dst], 1);
    return;
  }
  int e = i - Et;
  if (e < 128 * 256) {                        // W1 [128][256] -> W1T [256][128]
    int k = e >> 8, n = e & 255;
    W1T[n * 128 + k] = f2bf(W1[e]);
    return;
  }
  e -= 128 * 256;
  if (e < 256 * 64) {                         // W2 [256][64] -> W2T [64][256]
    int k = e >> 6, n = e & 63;
    W2T[n * 256 + k] = f2bf(W2[e]);
  }
}

__global__ void scan_partials_kernel(const int* __restrict__ deg,
                                     int* __restrict__ partials, int Ntot) {
  __shared__ int red[256];
  int t = threadIdx.x;
  int base = blockIdx.x * 1024 + t * 4;
  int s = 0;
  if (base + 3 < Ntot) {
    int4 v = *(const int4*)(deg + base);
    s = v.x + v.y + v.z + v.w;
  } else {
    for (int i = 0; i < 4; ++i)
      if (base + i < Ntot) s += deg[base + i];
  }
  red[t] = s;
  __syncthreads();
  for (int off = 128; off > 0; off >>= 1) {
    if (t < off) red[t] += red[t + off];
    __syncthreads();
  }
  if (t == 0) partials[blockIdx.x] = red[0];
}

__global__ void scan_final_kernel(const int* __restrict__ deg,
                                  const int* __restrict__ partials,
                                  int* __restrict__ rowptr,
                                  int* __restrict__ cursor, int Ntot, int NB) {
  __shared__ int sums[256];
  int t = threadIdx.x;
  int bid = blockIdx.x;
  int base = bid * 1024 + t * 4;
  int4 v = make_int4(0, 0, 0, 0);
  if (base + 3 < Ntot) {
    v = *(const int4*)(deg + base);
  } else {
    if (base + 0 < Ntot) v.x = deg[base + 0];
    if (base + 1 < Ntot) v.y = deg[base + 1];
    if (base + 2 < Ntot) v.z = deg[base + 2];
    if (base + 3 < Ntot) v.w = deg[base + 3];
  }
  sums[t] = v.x + v.y + v.z + v.w;
  __syncthreads();
  for (int off = 1; off < 256; off <<= 1) {
    int u = (t >= off) ? sums[t - off] : 0;
    __syncthreads();
    sums[t] += u;
    __syncthreads();
  }
  int boff = 0;
  for (int j = 0; j < bid; ++j) boff += partials[j];  // <=48 uniform iters
  int excl = boff + ((t == 0) ? 0 : sums[t - 1]);
  int4 r;
  r.x = excl;
  r.y = r.x + v.x;
  r.z = r.y + v.y;
  r.w = r.z + v.z;
  if (base + 3 < Ntot) {
    *(int4*)(rowptr + base) = r;
    *(int4*)(cursor + base) = r;
  } else {
    if (base + 0 < Ntot) { rowptr[base + 0] = r.x; cursor[base + 0] = r.x; }
    if (base + 1 < Ntot) { rowptr[base + 1] = r.y; cursor[base + 1] = r.y; }
    if (base + 2 < Ntot) { rowptr[base + 2] = r.z; cursor[base + 2] = r.z; }
    if (base + 3 < Ntot) { rowptr[base + 3] = r.w; cursor[base + 3] = r.w; }
  }
}

__global__ void scatter_edges_kernel(const int* __restrict__ ei, int E, int Nn,
                                     int* __restrict__ cursor, int* __restrict__ col) {
  int e = blockIdx.x * blockDim.x + threadIdx.x;
  if (e >= E + Nn) return;
  int src, dst;
  if (e < E) { src = ei[e]; dst = ei[E + e]; }
  else       { src = dst = e - E; }
  int pos = atomicAdd(&cursor[dst], 1);
  col[pos] = src;
}

// ---- GEMM1 fused: xl1 = bf16(x) @ W1, + alpha1 in epilogue ------------------
// BK=32 pipelined, grid (MB, 2), block 256 = 4 waves 2x2, wave tile 64x64.
// A staged fp32->bf16 on the fly. Head h = blockIdx.y*2 + wn/64 (= wave cols).

__global__ __launch_bounds__(256) void gemm1_fused_kernel(
    const float* __restrict__ x,      // [M][128] fp32
    const u16* __restrict__ w1t,      // [256][128] bf16
    const float* __restrict__ a_src,  // [4][64] fp32
    const float* __restrict__ a_dst,
    u16* __restrict__ C,              // [Mpad][256] bf16
    float* __restrict__ asrc, float* __restrict__ adst,  // [M*4]
    int M) {
  constexpr int BM = 128, BN = 128, BK = 32, PK = 40;
  __shared__ short As[BM][PK];
  __shared__ short Bs[BN][PK];
  int tid = threadIdx.x;
  int lane = tid & 63, w = tid >> 6;
  int q = lane >> 4, fr = lane & 15;
  int wm = (w >> 1) * 64, wn = (w & 1) * 64;
  int bm0 = blockIdx.x * BM, bn0 = blockIdx.y * BN;
  int fk = q * 8;

  f32x4 acc[4][4] = {};

  for (int k0 = 0; k0 < 128; k0 += BK) {
#pragma unroll
    for (int p = 0; p < 4; ++p) {              // A: 128x32 fp32 -> bf16
      int idx = p * 1024 + tid * 4;
      int r = idx >> 5, c = idx & 31;
      float4 v = make_float4(0.f, 0.f, 0.f, 0.f);
      if (bm0 + r < M) v = *(const float4*)(x + (size_t)(bm0 + r) * 128 + k0 + c);
      *(ushort4*)&As[r][c] = make_ushort4(f2bf(v.x), f2bf(v.y), f2bf(v.z), f2bf(v.w));
    }
#pragma unroll
    for (int p = 0; p < 2; ++p) {              // B: 128x32 bf16
      int idx = p * 2048 + tid * 8;
      int r = idx >> 5, c = idx & 31;
      *(s8v*)&Bs[r][c] = *(const s8v*)(w1t + (size_t)(bn0 + r) * 128 + k0 + c);
    }
    __syncthreads();

    s8v af[4], bf[4];
#pragma unroll
    for (int i = 0; i < 4; ++i)
      af[i] = *(const s8v*)&As[wm + i * 16 + fr][fk];
#pragma unroll
    for (int j = 0; j < 4; ++j)
      bf[j] = *(const s8v*)&Bs[wn + j * 16 + fr][fk];
#pragma unroll
    for (int i = 0; i < 4; ++i)
#pragma unroll
      for (int j = 0; j < 4; ++j)
        acc[i][j] = __builtin_amdgcn_mfma_f32_16x16x32_bf16(af[i], bf[j], acc[i][j], 0, 0, 0);
    __syncthreads();
  }

  // epilogue: alpha for head h (this wave's 64 cols) + C write
  int h = blockIdx.y * 2 + (wn >> 6);
  float asv[4], adv[4];
#pragma unroll
  for (int j = 0; j < 4; ++j) {
    asv[j] = a_src[h * 64 + j * 16 + fr];
    adv[j] = a_dst[h * 64 + j * 16 + fr];
  }
#pragma unroll
  for (int i = 0; i < 4; ++i) {
#pragma unroll
    for (int r = 0; r < 4; ++r) {
      int row = bm0 + wm + i * 16 + q * 4 + r;
      float ps = 0.f, pd = 0.f;
#pragma unroll
      for (int j = 0; j < 4; ++j) {
        ps = fmaf(acc[i][j][r], asv[j], ps);
        pd = fmaf(acc[i][j][r], adv[j], pd);
      }
#pragma unroll
      for (int mmask = 1; mmask < 16; mmask <<= 1) {
        ps += __shfl_xor(ps, mmask, 64);
        pd += __shfl_xor(pd, mmask, 64);
      }
      if (fr == 0 && row < M) {
        asrc[row * 4 + h] = ps * LOG2E;
        adst[row * 4 + h] = pd * LOG2E;
      }
    }
  }
#pragma unroll
  for (int i = 0; i < 4; ++i)
#pragma unroll
    for (int j = 0; j < 4; ++j)
#pragma unroll
      for (int r = 0; r < 4; ++r) {
        int row = bm0 + wm + i * 16 + q * 4 + r;
        if (row < M)
          C[(size_t)row * 256 + bn0 + wn + j * 16 + fr] = f2bf(acc[i][j][r]);
      }
}

// ---- GEMM2 fused: xl2 = hb @ W2, + alpha2 in epilogue (LDS cross-wave) ------

__global__ __launch_bounds__(256) void gemm2_fused_kernel(
    const u16* __restrict__ A,        // hb [Mpad][256] bf16
    const u16* __restrict__ Bt,       // w2t [64][256] bf16
    const float* __restrict__ a_src,  // [64]
    const float* __restrict__ a_dst,
    u16* __restrict__ C,              // [Mpad][64] bf16
    float* __restrict__ asrc, float* __restrict__ adst,  // [M]
    int M) {
  constexpr int BM = 128, BN = 64, BK = 32, PK = 40;
  __shared__ short As[BM][PK];
  __shared__ short Bs[BN][PK];
  __shared__ float alds[BM][4];
  int tid = threadIdx.x;
  int lane = tid & 63, w = tid >> 6;
  int q = lane >> 4, fr = lane & 15;
  int wm = (w >> 1) * 64, wn = (w & 1) * 32;
  int bm0 = blockIdx.x * BM;
  int fk = q * 8;

  f32x4 acc[4][2] = {};

  for (int k0 = 0; k0 < 256; k0 += BK) {
#pragma unroll
    for (int p = 0; p < 2; ++p) {
      int idx = p * 2048 + tid * 8;
      int r = idx / BK, c = idx % BK;
      *(s8v*)&As[r][c] = *(const s8v*)(A + (size_t)(bm0 + r) * 256 + k0 + c);
    }
    {
      int idx = tid * 8;
      int r = idx / BK, c = idx % BK;
      if (r < BN)
        *(s8v*)&Bs[r][c] = *(const s8v*)(Bt + (size_t)r * 256 + k0 + c);
    }
    __syncthreads();

    s8v af[4], bf[2];
#pragma unroll
    for (int i = 0; i < 4; ++i)
      af[i] = *(const s8v*)&As[wm + i * 16 + fr][fk];
#pragma unroll
    for (int j = 0; j < 2; ++j)
      bf[j] = *(const s8v*)&Bs[wn + j * 16 + fr][fk];
#pragma unroll
    for (int i = 0; i < 4; ++i)
#pragma unroll
      for (int j = 0; j < 2; ++j)
        acc[i][j] = __builtin_amdgcn_mfma_f32_16x16x32_bf16(af[i], bf[j], acc[i][j], 0, 0, 0);
    __syncthreads();
  }

  float asv[2], adv[2];
#pragma unroll
  for (int j = 0; j < 2; ++j) {
    asv[j] = a_src[wn + j * 16 + fr];
    adv[j] = a_dst[wn + j * 16 + fr];
  }
#pragma unroll
  for (int i = 0; i < 4; ++i) {
#pragma unroll
    for (int r = 0; r < 4; ++r) {
      int lr = wm + i * 16 + q * 4 + r;
      float ps = 0.f, pd = 0.f;
#pragma unroll
      for (int j = 0; j < 2; ++j) {
        ps = fmaf(acc[i][j][r], asv[j], ps);
        pd = fmaf(acc[i][j][r], adv[j], pd);
      }
#pragma unroll
      for (int mmask = 1; mmask < 16; mmask <<= 1) {
        ps += __shfl_xor(ps, mmask, 64);
        pd += __shfl_xor(pd, mmask, 64);
      }
      if (fr == 0) {
        alds[lr][(w & 1) * 2 + 0] = ps;
        alds[lr][(w & 1) * 2 + 1] = pd;
      }
    }
  }
#pragma unroll
  for (int i = 0; i < 4; ++i)
#pragma unroll
    for (int j = 0; j < 2; ++j)
#pragma unroll
      for (int r = 0; r < 4; ++r) {
        int row = bm0 + wm + i * 16 + q * 4 + r;
        if (row < M)
          C[(size_t)row * 64 + wn + j * 16 + fr] = f2bf(acc[i][j][r]);
      }
  __syncthreads();
  if (tid < BM) {
    int row = bm0 + tid;
    if (row < M) {
      asrc[row] = (alds[tid][0] + alds[tid][2]) * LOG2E;
      adst[row] = (alds[tid][1] + alds[tid][3]) * LOG2E;
    }
  }
}

// ---- layer-1 aggregation: half-wave (32 lanes) per node, 8 ch/lane ----------

__global__ void agg_multi_kernel(const u16* __restrict__ xlb,
                                 const float* __restrict__ asrc,
                                 const float* __restrict__ adst,
                                 const int* __restrict__ rowptr,
                                 const int* __restrict__ col,
                                 const float* __restrict__ bias,
                                 u16* __restrict__ hb, int Nn) {
  int n = blockIdx.x * 8 + (threadIdx.x >> 5);
  if (n >= Nn) return;
  int lane = threadIdx.x & 31;
  int h = lane >> 3;                          // 8 lanes per head
  float adn = adst[n * 4 + h];
  int beg = rowptr[n], end = rowptr[n + 1];

  float s = 0.f;
  float acc[8] = {};

  float as0 = 0.f, as1 = 0.f, as2 = 0.f, as3 = 0.f;
  uint4 v0 = {}, v1 = {}, v2 = {}, v3 = {};
  {
    int sc = col[beg];
    as0 = asrc[sc * 4 + h];
    v0 = *(const uint4*)(xlb + (size_t)sc * 256 + lane * 8);
    if (beg + 1 < end) {
      int c1 = col[beg + 1];
      as1 = asrc[c1 * 4 + h];
      v1 = *(const uint4*)(xlb + (size_t)c1 * 256 + lane * 8);
    }
    if (beg + 2 < end) {
      int c2 = col[beg + 2];
      as2 = asrc[c2 * 4 + h];
      v2 = *(const uint4*)(xlb + (size_t)c2 * 256 + lane * 8);
    }
    if (beg + 3 < end) {
      int c3 = col[beg + 3];
      as3 = asrc[c3 * 4 + h];
      v3 = *(const uint4*)(xlb + (size_t)c3 * 256 + lane * 8);
    }
  }

  for (int i = beg; i < end; ++i) {
    float e = as0 + adn;
    e = fmaxf(e, 0.2f * e);                   // leaky_relu (log2-scaled)
    uint4 vc = v0;
    as0 = as1; v0 = v1;                       // shift pipeline
    as1 = as2; v1 = v2;
    as2 = as3; v2 = v3;
    if (i + 4 < end) {
      int sc = col[i + 4];
      as3 = asrc[sc * 4 + h];
      v3 = *(const uint4*)(xlb + (size_t)sc * 256 + lane * 8);
    }
    float w = __builtin_amdgcn_exp2f(e);
    s += w;
    acc[0] = fmaf(w, bflo(vc.x), acc[0]);
    acc[1] = fmaf(w, bfhi(vc.x), acc[1]);
    acc[2] = fmaf(w, bflo(vc.y), acc[2]);
    acc[3] = fmaf(w, bfhi(vc.y), acc[3]);
    acc[4] = fmaf(w, bflo(vc.z), acc[4]);
    acc[5] = fmaf(w, bfhi(vc.z), acc[5]);
    acc[6] = fmaf(w, bflo(vc.w), acc[6]);
    acc[7] = fmaf(w, bfhi(vc.w), acc[7]);
  }
  float inv_s = 1.f / s;

  float4 b0 = *(const float4*)(bias + lane * 8);
  float4 b1f = *(const float4*)(bias + lane * 8 + 4);
  float bb[8] = {b0.x, b0.y, b0.z, b0.w, b1f.x, b1f.y, b1f.z, b1f.w};
  u16 ov[8];
#pragma unroll
  for (int j = 0; j < 8; ++j) {
    float o = fmaf(acc[j], inv_s, bb[j]);
    o = (o > 0.f) ? o : __expf(o) - 1.f;      // ELU
    ov[j] = f2bf(o);
  }
  *(uint4*)(hb + (size_t)n * 256 + lane * 8) = *(uint4*)ov;
}

// ---- layer-2 aggregation: 8 lanes/node, uint4 = full 128B row, depth-3 ------

__global__ void agg_single_kernel(const u16* __restrict__ xlb,
                                  const float* __restrict__ asrc,
                                  const float* __restrict__ adst,
                                  const int* __restrict__ rowptr,
                                  const int* __restrict__ col,
                                  const float* __restrict__ bias,
                                  float* __restrict__ out, int Nn) {
  int n = blockIdx.x * 32 + (threadIdx.x >> 3);
  if (n >= Nn) return;
  int lane = threadIdx.x & 7;                 // 8 lanes, 8 ch each
  float adn = adst[n];
  int beg = rowptr[n], end = rowptr[n + 1];

  float s = 0.f;
  float acc[8] = {};

  float as0 = 0.f, as1 = 0.f, as2 = 0.f;
  uint4 v0 = {}, v1 = {}, v2 = {};
  {
    int sc = col[beg];
    as0 = asrc[sc];
    v0 = *(const uint4*)(xlb + (size_t)sc * 64 + lane * 8);
    if (beg + 1 < end) {
      int c1 = col[beg + 1];
      as1 = asrc[c1];
      v1 = *(const uint4*)(xlb + (size_t)c1 * 64 + lane * 8);
    }
    if (beg + 2 < end) {
      int c2 = col[beg + 2];
      as2 = asrc[c2];
      v2 = *(const uint4*)(xlb + (size_t)c2 * 64 + lane * 8);
    }
  }

  for (int i = beg; i < end; ++i) {
    float e = as0 + adn;
    e = fmaxf(e, 0.2f * e);
    uint4 vc = v0;
    as0 = as1; v0 = v1;                       // shift pipeline
    as1 = as2; v1 = v2;
    if (i + 3 < end) {
      int sc = col[i + 3];
      as2 = asrc[sc];
      v2 = *(const uint4*)(xlb + (size_t)sc * 64 + lane * 8);
    }
    float w = __builtin_amdgcn_exp2f(e);
    s += w;
    acc[0] = fmaf(w, bflo(vc.x), acc[0]);
    acc[1] = fmaf(w, bfhi(vc.x), acc[1]);
    acc[2] = fmaf(w, bflo(vc.y), acc[2]);
    acc[3] = fmaf(w, bfhi(vc.y), acc[3]);
    acc[4] = fmaf(w, bflo(vc.z), acc[4]);
    acc[5] = fmaf(w, bfhi(vc.z), acc[5]);
    acc[6] = fmaf(w, bflo(vc.w), acc[6]);
    acc[7] = fmaf(w, bfhi(vc.w), acc[7]);
  }
  float inv_s = 1.f / s;

  const float* bp = bias + lane * 8;
  float4 o0, o1;
  o0.x = fmaf(acc[0], inv_s, bp[0]);
  o0.y = fmaf(acc[1], inv_s, bp[1]);
  o0.z = fmaf(acc[2], inv_s, bp[2]);
  o0.w = fmaf(acc[3], inv_s, bp[3]);
  o1.x = fmaf(acc[4], inv_s, bp[4]);
  o1.y = fmaf(acc[5], inv_s, bp[5]);
  o1.z = fmaf(acc[6], inv_s, bp[6]);
  o1.w = fmaf(acc[7], inv_s, bp[7]);
  *(float4*)(out + (size_t)n * 64 + lane * 8) = o0;
  *(float4*)(out + (size_t)n * 64 + lane * 8 + 4) = o1;
}

// ---------------------------------------------------------------------------

extern "C" void kernel_launch(void* const* d_in, const int* in_sizes, int n_in,
                              void* d_out, int out_size, void* d_ws, size_t ws_size,
                              hipStream_t stream) {
  const float* x   = (const float*)d_in[0];
  const int*   ei  = (const int*)d_in[1];
  const float* W1  = (const float*)d_in[2];
  const float* as1 = (const float*)d_in[3];
  const float* ad1 = (const float*)d_in[4];
  const float* b1  = (const float*)d_in[5];
  const float* W2  = (const float*)d_in[6];
  const float* as2 = (const float*)d_in[7];
  const float* ad2 = (const float*)d_in[8];
  const float* b2  = (const float*)d_in[9];
  float* out = (float*)d_out;

  const int Nn = in_sizes[0] / 128;  // 50000
  const int E  = in_sizes[1] / 2;    // 800000
  const int Et = E + Nn;
  const int Ntot = Nn + 1;           // scan domain (virtual deg[Nn]=0)
  const int NB = (Ntot + 1023) / 1024;
  const int MB = (Nn + 127) / 128;
  const int Mpad = MB * 128;

  char* base = (char*)d_ws;
  size_t off = 0;
  auto alloc = [&](size_t bytes) -> void* {
    void* p = base + off;
    off = (off + bytes + 255) & ~(size_t)255;
    return p;
  };
  u16*   w1t      = (u16*)alloc((size_t)256 * 128 * 2);    // W1^T bf16 [256][128]
  u16*   w2t      = (u16*)alloc((size_t)64 * 256 * 2);     // W2^T bf16 [64][256]
  u16*   xlb1     = (u16*)alloc((size_t)Mpad * 256 * 2);   // x@W1, bf16
  u16*   hb       = (u16*)alloc((size_t)Mpad * 256 * 2);   // ELU output, bf16
  float* asrc1    = (float*)alloc((size_t)Nn * 4 * 4);
  float* adst1    = (float*)alloc((size_t)Nn * 4 * 4);
  float* asrc2    = (float*)alloc((size_t)Nn * 4);
  float* adst2    = (float*)alloc((size_t)Nn * 4);
  int*   deg      = (int*)alloc((size_t)(Ntot + 8) * 4);
  int*   rowptr   = (int*)alloc((size_t)(Ntot + 8) * 4);
  int*   cursor   = (int*)alloc((size_t)(Ntot + 8) * 4);
  int*   partials = (int*)alloc(256 * 4);
  int*   col      = (int*)alloc((size_t)Et * 4);
  u16*   xlb2     = xlb1;  // layer2 h@W2 bf16 [Mpad][64], aliases xlb1

  // --- CSR build + W prep (5 small dispatches; launch gaps measured ~1-2us) ---
  hipMemsetAsync(deg, 0, (size_t)Ntot * 4, stream);
  {
    int tot = Et + 128 * 256 + 256 * 64;
    prep_count_kernel<<<(tot + 255) / 256, 256, 0, stream>>>(
        ei, E, Nn, deg, W1, w1t, W2, w2t);
  }
  scan_partials_kernel<<<NB, 256, 0, stream>>>(deg, partials, Ntot);
  scan_final_kernel<<<NB, 256, 0, stream>>>(deg, partials, rowptr, cursor, Ntot, NB);
  scatter_edges_kernel<<<(Et + 255) / 256, 256, 0, stream>>>(ei, E, Nn, cursor, col);

  // --- layer 1 ---
  {
    dim3 grid(MB, 2);
    gemm1_fused_kernel<<<grid, 256, 0, stream>>>(x, w1t, as1, ad1, xlb1, asrc1, adst1, Nn);
  }
  agg_multi_kernel<<<(Nn + 7) / 8, 256, 0, stream>>>(xlb1, asrc1, adst1, rowptr, col, b1, hb, Nn);

  // --- layer 2 ---
  gemm2_fused_kernel<<<MB, 256, 0, stream>>>(hb, w2t, as2, ad2, xlb2, asrc2, adst2, Nn);
  agg_single_kernel<<<(Nn + 31) / 32, 256, 0, stream>>>(xlb2, asrc2, adst2, rowptr, col, b2, out, Nn);
}